// Round 4
// baseline (10682.945 us; speedup 1.0000x reference)
//
#include <hip/hip_runtime.h>

// EvolvedNet: 32-node graph relaxation, 128 edges applied sequentially per
// sweep, 32 sweeps, batched over 524288 independent elements.
//
// R1: 743us @ BLOCK=256/EPT=1: VALU-bound (91%), 49.5 VALU cy/wave-edge.
// R2: wave-uniform saturation branch: REGRESSED (1230us) — per-edge branch
//     fragmented the loop. Inner loop must stay branch-free.
// R3: BLOCK=64/EPT=2 float2: REGRESSED (833us) — LDS/elem is fixed 128B, so
//     EPT=2 halved occupancy (41%->20%), latency-bound (VALUBusy 57%).
// R4: BLOCK=256/EPT=1 (occupancy back) + prep-kernel scalar hoists
//     (byte offsets, w*2log2e) + ds_add_f32 accumulate (atomicAdd on own LDS
//     column; in-order DS pipe preserves sequential edge semantics; IEEE RTN
//     rounding identical to explicit add).
//     Per-edge VALU: 2 addr adds + mul + add + fma = 10cy + exp + rcp.

#define N_NODES   32
#define N_INPUTS  8
#define N_OUTPUTS 4
#define N_EDGES   128
#define BATCH     524288
#define BLOCK     256

// 2 * log2(e)
#define TWO_LOG2E 2.88539008177792681472f

__device__ __forceinline__ float sread_f(const float* p) {
    return __int_as_float(__builtin_amdgcn_readfirstlane(__float_as_int(*p)));
}

// Pre-kernel: per-edge uniform precompute into d_ws (graph-capture safe,
// deterministic, runs every call). Byte offsets of each node's LDS row.
__global__ void EvolvedNet_prep(const float* __restrict__ w,
                                const int*   __restrict__ src,
                                const int*   __restrict__ dst,
                                int* __restrict__ soff, int* __restrict__ doff,
                                float* __restrict__ wk) {
    const int e = threadIdx.x;
    if (e < N_EDGES) {
        soff[e] = src[e] * (BLOCK * 4);  // byte offset of node row in LDS
        doff[e] = dst[e] * (BLOCK * 4);
        wk[e]   = w[e] * TWO_LOG2E;      // same f32 op as before -> bit-same
    }
}

__global__ __launch_bounds__(BLOCK)
void EvolvedNet_80032420593868_kernel(const float* __restrict__ x,
                                      const int*   __restrict__ soff,
                                      const int*   __restrict__ doff,
                                      const float* __restrict__ wk,
                                      float*       __restrict__ out) {
    // vals[node][tid]: wave-uniform node index -> lanes hit consecutive
    // banks (2-way aliasing across wave64 = free).
    __shared__ float vals[N_NODES][BLOCK];

    const int tid = threadIdx.x;
    const int b   = blockIdx.x * BLOCK + tid;

    // base byte address of this thread's column
    char* lds_base = (char*)&vals[0][0] + tid * 4;

#pragma unroll
    for (int n = 0; n < N_INPUTS; ++n)
        vals[n][tid] = x[n * BATCH + b];
#pragma unroll
    for (int n = N_INPUTS; n < N_NODES; ++n)
        vals[n][tid] = 0.0f;

    // No __syncthreads needed: each thread touches only its own column;
    // per-thread DS ops execute in order (sequential edge semantics).

    for (int sweep = 0; sweep < N_NODES; ++sweep) {
#pragma unroll 8
        for (int e = 0; e < N_EDGES; ++e) {
            const int   so = __builtin_amdgcn_readfirstlane(soff[e]);
            const int   dd = __builtin_amdgcn_readfirstlane(doff[e]);
            const float wv = sread_f(&wk[e]);

            const float v = *(const float*)(lds_base + so);
            const float a = v * wv;
            const float u = __builtin_amdgcn_exp2f(a);
            const float r = __builtin_amdgcn_rcpf(1.0f + u);
            const float t = 1.0f - 2.0f * r;          // contracts to fma

            // ds_add_f32 on own column: no read-modify-write chain, no
            // cross-thread sharing; DS pipe in-order -> later edges see it.
            atomicAdd((float*)(lds_base + dd), t);
        }
    }

    // outputs: tanh(vals[28..31]); out is [N_OUTPUTS][BATCH] flat.
#pragma unroll
    for (int o = 0; o < N_OUTPUTS; ++o) {
        const float v = vals[N_NODES - N_OUTPUTS + o][tid];
        const float u = __builtin_amdgcn_exp2f(v * TWO_LOG2E);
        out[o * BATCH + b] = 1.0f - 2.0f * __builtin_amdgcn_rcpf(1.0f + u);
    }
}

extern "C" void kernel_launch(void* const* d_in, const int* in_sizes, int n_in,
                              void* d_out, int out_size, void* d_ws, size_t ws_size,
                              hipStream_t stream) {
    const float* x   = (const float*)d_in[0];
    const float* w   = (const float*)d_in[1];
    const int*   src = (const int*)d_in[2];
    const int*   dst = (const int*)d_in[3];
    float*       out = (float*)d_out;

    // d_ws layout: soff[128] | doff[128] | wk[128]  (1.5 KB)
    int*   soff = (int*)d_ws;
    int*   doff = soff + N_EDGES;
    float* wkp  = (float*)(doff + N_EDGES);

    EvolvedNet_prep<<<1, 128, 0, stream>>>(w, src, dst, soff, doff, wkp);

    const int grid = BATCH / BLOCK;  // 2048 blocks, exact
    EvolvedNet_80032420593868_kernel<<<grid, BLOCK, 0, stream>>>(x, soff, doff, wkp, out);
}

// Round 5
// 786.333 us; speedup vs baseline: 13.5858x; 13.5858x over previous
//
#include <hip/hip_runtime.h>

// EvolvedNet: 32-node graph relaxation, 128 edges applied sequentially per
// sweep, 32 sweeps, batched over 524288 independent elements.
//
// R1: 743us @ BLOCK=256/EPT=1. VALU-bound 91%; 49.5 issue-cy/elem-edge;
//     exp+rcp ~16cy each = 70% of cost.
// R2: wave-uniform saturation branch REGRESSED (1230us): per-edge branch
//     fragmented the loop. Inner loop stays branch-free.
// R3: BLOCK=64/EPT=2 f32x2: packing worked (70 issue-cy/edge-pair = 35/elem)
//     but occupancy halved (1.6 waves/SIMD) -> latency-bound 57% busy, 833us.
// R4: LDS atomicAdd via char* pointer: CATASTROPHIC (10.7ms) — generic-AS
//     pointer defeated ds_add lowering -> flat atomics. Never cast LDS
//     pointers; typed __shared__ indexing only.
// R5: R3's f32x2 packing + R1's occupancy: BLOCK=128/EPT=2 -> 32KB LDS/block,
//     5 blocks/CU (160KB exact) = 2.5 waves/SIMD x 2 streams each. Plain
//     uniform loads (no readfirstlane), native f32x2 vector ops to force
//     v_pk_*_f32, early dst load to shorten the dependent tail.

#define N_NODES   32
#define N_INPUTS  8
#define N_OUTPUTS 4
#define N_EDGES   128
#define BATCH     524288
#define BLOCK     128                // threads per block (2 waves)
#define EPT       2                  // batch elements per thread
#define TILE      (BLOCK * EPT)      // 256 elements per block

// 2 * log2(e)
#define TWO_LOG2E 2.88539008177792681472f

typedef float f32x2 __attribute__((ext_vector_type(2)));

// Pre-kernel: per-edge uniform precompute into d_ws (graph-safe, runs every
// call, deterministic). soff/doff are f32x2-element row offsets.
__global__ void EvolvedNet_prep(const float* __restrict__ w,
                                const int*   __restrict__ src,
                                const int*   __restrict__ dst,
                                int* __restrict__ soff, int* __restrict__ doff,
                                float* __restrict__ wk) {
    const int e = threadIdx.x;
    if (e < N_EDGES) {
        soff[e] = src[e] * BLOCK;        // row offset in f32x2 elements
        doff[e] = dst[e] * BLOCK;
        wk[e]   = w[e] * TWO_LOG2E;      // same f32 op as R1 -> bit-identical
    }
}

__global__ __launch_bounds__(BLOCK)
void EvolvedNet_80032420593868_kernel(const float* __restrict__ x,
                                      const int*   __restrict__ soff,
                                      const int*   __restrict__ doff,
                                      const float* __restrict__ wk,
                                      float*       __restrict__ out) {
    // vals[node*BLOCK + tid]: per-thread f32x2 column (2 adjacent batch
    // elements). Wave-uniform node index -> lanes hit sequential 8B slots:
    // conflict-free. Typed LDS indexing ONLY (R4 lesson).
    __shared__ f32x2 vals[N_NODES * BLOCK];

    const int tid = threadIdx.x;
    const int b0  = blockIdx.x * TILE + tid * 2;

    // init: inputs into nodes 0..7 (8B coalesced loads), zeros elsewhere.
#pragma unroll
    for (int n = 0; n < N_INPUTS; ++n)
        vals[n * BLOCK + tid] = *(const f32x2*)&x[n * BATCH + b0];
#pragma unroll
    for (int n = N_INPUTS; n < N_NODES; ++n)
        vals[n * BLOCK + tid] = (f32x2)(0.0f, 0.0f);

    // No __syncthreads needed: each thread touches only its own column;
    // per-thread DS ops execute in order (sequential edge semantics kept).

    for (int sweep = 0; sweep < N_NODES; ++sweep) {
#pragma unroll 8
        for (int e = 0; e < N_EDGES; ++e) {
            const int   so = soff[e];    // uniform -> s_load + s_lshl (SALU)
            const int   dd = doff[e];
            const float wv = wk[e];

            const f32x2 v  = vals[so + tid];
            const f32x2 dv = vals[dd + tid];   // load dst early (alias-safe:
                                               // sees all prior edge writes)
            const f32x2 a  = v * wv;           // v_pk_mul_f32
            f32x2 u;
            u.x = __builtin_amdgcn_exp2f(a.x);
            u.y = __builtin_amdgcn_exp2f(a.y);
            const f32x2 s1 = 1.0f + u;         // v_pk_add_f32
            f32x2 r;
            r.x = __builtin_amdgcn_rcpf(s1.x);
            r.y = __builtin_amdgcn_rcpf(s1.y);
            const f32x2 t = 1.0f - 2.0f * r;   // v_pk_fma_f32
            vals[dd + tid] = dv + t;           // v_pk_add_f32 + ds_write_b64
        }
    }

    // outputs: tanh(vals[28..31]); out is [N_OUTPUTS][BATCH] flat, 8B stores.
#pragma unroll
    for (int o = 0; o < N_OUTPUTS; ++o) {
        const f32x2 v = vals[(N_NODES - N_OUTPUTS + o) * BLOCK + tid];
        f32x2 t;
        t.x = 1.0f - 2.0f * __builtin_amdgcn_rcpf(1.0f + __builtin_amdgcn_exp2f(v.x * TWO_LOG2E));
        t.y = 1.0f - 2.0f * __builtin_amdgcn_rcpf(1.0f + __builtin_amdgcn_exp2f(v.y * TWO_LOG2E));
        *(f32x2*)&out[o * BATCH + b0] = t;
    }
}

extern "C" void kernel_launch(void* const* d_in, const int* in_sizes, int n_in,
                              void* d_out, int out_size, void* d_ws, size_t ws_size,
                              hipStream_t stream) {
    const float* x   = (const float*)d_in[0];
    const float* w   = (const float*)d_in[1];
    const int*   src = (const int*)d_in[2];
    const int*   dst = (const int*)d_in[3];
    float*       out = (float*)d_out;

    // d_ws layout: soff[128] | doff[128] | wk[128]  (1.5 KB)
    int*   soff = (int*)d_ws;
    int*   doff = soff + N_EDGES;
    float* wkp  = (float*)(doff + N_EDGES);

    EvolvedNet_prep<<<1, 128, 0, stream>>>(w, src, dst, soff, doff, wkp);

    const int grid = BATCH / TILE;   // 2048 blocks, exact
    EvolvedNet_80032420593868_kernel<<<grid, BLOCK, 0, stream>>>(x, soff, doff, wkp, out);
}